// Round 9
// baseline (1351.794 us; speedup 1.0000x reference)
//
#include <hip/hip_runtime.h>

// RVQ, MI355X round 9. r8's cheap screening loop (hi-only fp16 MFMA, u32-key
// top-4, 1 barrier/ct) + r4's PROVEN-clean memory pattern: full-1KB-row
// stores, coalesced L3-hot rin re-read in epilogue, 2 blocks/CU.
// Near-ties (margin 0.40) re-ranked by bit-exact numpy-fp32 emulator.
// ws: [0,2MB) hi frags f16 [4][64 ct][8 j][64 lane][8]
//     [2MB,+16KB) e2b = sum(e^2)+512 ; then f64 loss[4]

#define NUM_Q   4
#define KCODE   1024
#define DIM     256
#define NROWS   131072
#define QELEMS  33554432
#define MARGIN_FLAG 0.40f
#define KMASK   0xFFFFFC00u

typedef _Float16 f16x8 __attribute__((ext_vector_type(8)));
typedef float    f32x4 __attribute__((ext_vector_type(4)));

__device__ __forceinline__ float dqk(unsigned k) { return __uint_as_float(k & KMASK); }
__device__ __forceinline__ unsigned umin2(unsigned a, unsigned b) { return a < b ? a : b; }
__device__ __forceinline__ unsigned umax2(unsigned a, unsigned b) { return a > b ? a : b; }

// ---------------------------------------------------------------- prep
__global__ __launch_bounds__(64) void rvq_prep(const float* __restrict__ emb,
                                               _Float16* __restrict__ efrag,
                                               float* __restrict__ e2b,
                                               double* __restrict__ loss)
{
    const int bid  = blockIdx.x;            // layer*64 + ct
    const int lane = threadIdx.x;
    const int layer = bid >> 6;
    const int c = (bid & 63)*16 + (lane & 15);
    const int g = lane >> 4;
    const float* ep = emb + ((size_t)layer*KCODE + c)*DIM;

    double s2 = 0.0;
    #pragma unroll
    for (int j = 0; j < 8; ++j) {
        const int k0 = j*32 + 8*g;
        float4 a = *(const float4*)(ep + k0);
        float4 b = *(const float4*)(ep + k0 + 4);
        float v[8] = {a.x,a.y,a.z,a.w,b.x,b.y,b.z,b.w};
        f16x8 hh;
        #pragma unroll
        for (int x = 0; x < 8; ++x) {
            double dv = (double)v[x];
            s2 += dv*dv;
            hh[x] = (_Float16)(-2.0f*v[x]);          // fold -2 exactly
        }
        *(f16x8*)(efrag + ((size_t)(bid*8 + j)*64 + lane)*8) = hh;
    }
    s2 += __shfl_xor(s2, 16);
    s2 += __shfl_xor(s2, 32);
    if (g == 0) e2b[layer*KCODE + c] = (float)(s2 + 512.0);  // bias keeps keys positive
    if (bid == 0 && lane < 4) loss[lane] = 0.0;
}

// ------------- bit-exact numpy fp32 distance (validated r4-r8) -------------
__device__ __forceinline__ float np_sq128(const float* p) {
    #pragma clang fp contract(off)
    float s[16], U[4];
    #pragma unroll
    for (int l = 0; l < 16; ++l) {
        s[l] = ((p[l]*p[l] + p[16+l]*p[16+l]) + (p[32+l]*p[32+l] + p[48+l]*p[48+l]))
             + ((p[64+l]*p[64+l] + p[80+l]*p[80+l]) + (p[96+l]*p[96+l] + p[112+l]*p[112+l]));
    }
    #pragma unroll
    for (int i = 0; i < 4; ++i) U[i] = (s[i] + s[i+8]) + (s[i+4] + s[i+12]);
    return (U[0] + U[2]) + (U[1] + U[3]);
}
__device__ __forceinline__ float np_dist(const float* rp, const float* ep) {
    #pragma clang fp contract(off)
    float m = 0.f;
    #pragma unroll
    for (int kb = 0; kb < 16; ++kb) {          // batched loads, exact FMA order
        float a[16];
        #pragma unroll
        for (int x = 0; x < 4; ++x) {
            float4 v = *(const float4*)(ep + kb*16 + x*4);
            a[x*4+0]=v.x; a[x*4+1]=v.y; a[x*4+2]=v.z; a[x*4+3]=v.w;
        }
        #pragma unroll
        for (int x = 0; x < 16; ++x) m = __builtin_fmaf(rp[kb*16+x], a[x], m);
    }
    float se = np_sq128(ep) + np_sq128(ep + 128);
    float sr = np_sq128(rp) + np_sq128(rp + 128);
    return (sr + se) - 2.0f*m;
}

// ---------------------------------------------------------------- layer
__global__ __launch_bounds__(256, 2) void rvq_layer(
    const float* __restrict__ rin, float* __restrict__ rout,
    const float* __restrict__ emb, const _Float16* __restrict__ efrag,
    const float* __restrict__ e2b, float* __restrict__ idx_out,
    double* __restrict__ loss_slot, const float* __restrict__ xin)
{
    __shared__ __align__(16) _Float16 lt[2][8][64][8];   // 2 x 8KB dbuf
    __shared__ __align__(16) float    e2l[KCODE];
    __shared__ __align__(16) float    s_remu[4][DIM];
    __shared__ double wsum[4];

    const int tid  = threadIdx.x;
    const int w    = tid >> 6;
    const int lane = tid & 63;
    const int col  = lane & 15;
    const int g    = lane >> 4;
    const int r0   = blockIdx.x*128 + w*32;   // 32 rows per wave

    *(f32x4*)(e2l + tid*4) = *(const f32x4*)(e2b + tid*4);

    // B-fragments: 32 rows, hi fp16 only (64 VGPR)
    f16x8 rh[2][8];
    #pragma unroll
    for (int t = 0; t < 2; ++t) {
        const float* rp = rin + (size_t)(r0 + 16*t + col)*DIM + 8*g;
        #pragma unroll
        for (int j = 0; j < 8; ++j) {
            float4 a = *(const float4*)(rp + j*32);
            float4 b = *(const float4*)(rp + j*32 + 4);
            float v[8] = {a.x,a.y,a.z,a.w,b.x,b.y,b.z,b.w};
            #pragma unroll
            for (int x = 0; x < 8; ++x) rh[t][j][x] = (_Float16)v[x];
        }
    }

    // stage tile 0 (frag-ordered in global => linear copy)
    const uint4* gsrc = (const uint4*)efrag;             // 512 uint4 / 8KB tile
    {
        uint4 s0 = gsrc[tid], s1 = gsrc[256 + tid];
        uint4* lw = (uint4*)&lt[0][0][0][0];
        lw[tid] = s0; lw[256 + tid] = s1;
    }
    __syncthreads();

    unsigned k1[2] = {~0u, ~0u}, k2[2] = {~0u, ~0u};
    unsigned k3[2] = {~0u, ~0u}, k4[2] = {~0u, ~0u};
    const unsigned kor = (unsigned)(g << 2);

    for (int ct = 0; ct < 64; ++ct) {
        const int cur = ct & 1;
        uint4 p0, p1;
        if (ct < 63) {                       // prefetch next tile to regs
            p0 = gsrc[(ct+1)*512 + tid];
            p1 = gsrc[(ct+1)*512 + 256 + tid];
        }
        f32x4 e2v = *(const f32x4*)(e2l + ct*16 + 4*g);
        f32x4 acc[2] = {e2v, e2v};           // C-init = e2 + 512
        #pragma unroll
        for (int j = 0; j < 8; ++j) {
            f16x8 ah = *(const f16x8*)&lt[cur][j][lane][0];
            acc[0] = __builtin_amdgcn_mfma_f32_16x16x32_f16(ah, rh[0][j], acc[0], 0,0,0);
            acc[1] = __builtin_amdgcn_mfma_f32_16x16x32_f16(ah, rh[1][j], acc[1], 0,0,0);
        }
        const unsigned ctb = (unsigned)(ct << 4);
        #pragma unroll
        for (int t = 0; t < 2; ++t) {
            #pragma unroll
            for (int r = 0; r < 4; ++r) {
                unsigned key = (__float_as_uint(acc[t][r]) & KMASK) | kor | (ctb + (unsigned)r);
                unsigned a1 = umin2(k1[t], key), b1 = umax2(k1[t], key); k1[t] = a1;
                unsigned a2 = umin2(k2[t], b1),  b2 = umax2(k2[t], b1);  k2[t] = a2;
                unsigned a3 = umin2(k3[t], b2),  b3 = umax2(k3[t], b2);  k3[t] = a3;
                k4[t] = umin2(k4[t], b3);
            }
        }
        if (ct < 63) {                       // single barrier per tile (dbuf-safe)
            uint4* lw = (uint4*)&lt[cur^1][0][0][0];
            lw[tid] = p0; lw[256 + tid] = p1;
        }
        __syncthreads();
    }

    // per-row min, flags, re-rank, index write
    int fidx[2];
    #pragma unroll
    for (int t = 0; t < 2; ++t) {
        unsigned gm = k1[t];
        gm = umin2(gm, __shfl_xor(gm, 16));
        gm = umin2(gm, __shfl_xor(gm, 32));
        float thr = dqk(gm) + MARGIN_FLAG;
        bool c1 = (k1[t] != gm) && (dqk(k1[t]) < thr);
        bool c2 = dqk(k2[t]) < thr;
        bool c3 = dqk(k3[t]) < thr;
        bool c4 = dqk(k4[t]) < thr;
        unsigned long long b = __ballot(c1 || c2 || c3 || c4);
        unsigned rowm = (unsigned)((b | (b>>16) | (b>>32) | (b>>48)) & 0xFFFFull);
        fidx[t] = (int)(gm & 1023u);

        unsigned m = rowm;
        while (m) {
            int p = __ffs(m) - 1; m &= m - 1;
            int row = r0 + 16*t + p;
            float4 rv = *(const float4*)(rin + (size_t)row*DIM + 4*lane);  // L3-hot
            *(float4*)&s_remu[w][4*lane] = rv;
            asm volatile("s_waitcnt lgkmcnt(0)" ::: "memory");
            int srcl = ((lane & 12) << 2) | p;          // 16 eval lanes
            unsigned s1 = __shfl(k1[t], srcl), s2 = __shfl(k2[t], srcl);
            unsigned s3 = __shfl(k3[t], srcl), s4 = __shfl(k4[t], srcl);
            int slot = lane & 3;
            unsigned ksel = slot == 0 ? s1 : (slot == 1 ? s2 : (slot == 2 ? s3 : s4));
            float thr_p = __shfl(thr, p);
            bool valid = (lane < 16) && (dqk(ksel) < thr_p);
            float d = 3.4e38f;
            int   cc = 0x7FFFFFFF;
            if (valid) {
                cc = (int)(ksel & 1023u);
                d  = np_dist(&s_remu[w][0], emb + (size_t)cc*DIM);
            }
            #pragma unroll
            for (int off = 1; off < 64; off <<= 1) {
                float od = __shfl_xor(d, off);
                int   oc = __shfl_xor(cc, off);
                if (od < d || (od == d && oc < cc)) { d = od; cc = oc; }
            }
            if (col == p) fidx[t] = cc;
        }
        if (lane < 16) idx_out[r0 + 16*t + lane] = (float)fidx[t];
    }

    // epilogue (r4-proven clean): per-row full-1KB coalesced; exact fp32
    // 3-op chain; last layer writes x - r'.
    const bool last = (xin != nullptr);
    double lacc = 0.0;
    #pragma unroll 4
    for (int i = 0; i < 32; ++i) {
        #pragma clang fp contract(off)
        int kr = __shfl((i < 16) ? fidx[0] : fidx[1], i & 15);
        int row = r0 + i;
        float4 rv = *(const float4*)(rin + (size_t)row*DIM + 4*lane);
        float4 ev = *(const float4*)(emb + (size_t)kr*DIM + 4*lane);
        float t0 = ev.x - rv.x, t1 = ev.y - rv.y, t2 = ev.z - rv.z, t3 = ev.w - rv.w;
        float q0 = rv.x + t0,  q1 = rv.y + t1,  q2 = rv.z + t2,  q3 = rv.w + t3;
        float4 nv;
        nv.x = rv.x - q0; nv.y = rv.y - q1; nv.z = rv.z - q2; nv.w = rv.w - q3;
        if (last) {
            float4 xv = *(const float4*)(xin + (size_t)row*DIM + 4*lane);
            nv.x = xv.x - nv.x; nv.y = xv.y - nv.y; nv.z = xv.z - nv.z; nv.w = xv.w - nv.w;
        }
        *(float4*)(rout + (size_t)row*DIM + 4*lane) = nv;
        lacc += (double)(t0*t0) + (double)(t1*t1) + (double)(t2*t2) + (double)(t3*t3);
    }
    #pragma unroll
    for (int o = 32; o; o >>= 1) lacc += __shfl_xor(lacc, o);
    if (lane == 0) wsum[w] = lacc;
    __syncthreads();
    if (tid == 0) atomicAdd(loss_slot, wsum[0]+wsum[1]+wsum[2]+wsum[3]);
}

// ---------------------------------------------------------------- loss finalize
__global__ void rvq_loss(const double* __restrict__ loss, float* __restrict__ lossout)
{
    double tot = (loss[0]+loss[1]+loss[2]+loss[3]) * (1.0/(double)QELEMS);
    lossout[0] = (float)(1.25*tot);
    lossout[1] = (float)(0.25*tot);
    lossout[2] = (float)tot;
}

// ---------------------------------------------------------------- launch
extern "C" void kernel_launch(void* const* d_in, const int* in_sizes, int n_in,
                              void* d_out, int out_size, void* d_ws, size_t ws_size,
                              hipStream_t stream)
{
    (void)in_sizes; (void)n_in; (void)out_size; (void)ws_size;
    const float* x   = (const float*)d_in[0];
    const float* emb = (const float*)d_in[1];
    float* out      = (float*)d_out;
    float* rbuf     = out;
    float* idx_base = out + QELEMS;
    float* loss_out = out + QELEMS + (size_t)NUM_Q*NROWS;

    _Float16* efrag = (_Float16*)d_ws;                              // 2 MB
    float*    e2b   = (float*)((char*)d_ws + 2u*1024u*1024u);       // 16 KB
    double*   loss  = (double*)((char*)d_ws + 2u*1024u*1024u + 16384u);

    rvq_prep<<<NUM_Q*64, 64, 0, stream>>>(emb, efrag, e2b, loss);
    for (int q = 0; q < NUM_Q; ++q) {
        rvq_layer<<<NROWS/128, 256, 0, stream>>>(
            (q == 0) ? x : rbuf, rbuf,
            emb   + (size_t)q*KCODE*DIM,
            efrag + (size_t)q*64*4096,
            e2b   + (size_t)q*KCODE,
            idx_base + (size_t)q*NROWS,
            loss + q,
            (q == NUM_Q-1) ? x : nullptr);
    }
    rvq_loss<<<1, 1, 0, stream>>>(loss, loss_out);
}

// Round 10
// 903.734 us; speedup vs baseline: 1.4958x; 1.4958x over previous
//
#include <hip/hip_runtime.h>

// RVQ, MI355X round 10: FUSED 4-layer kernel. Rows held fp32 in registers
// across all layers (no residual round-trips through HBM); per layer:
// r9-proven MFMA screen (hi-fp16, u32-key top-4) -> r8-proven np-fp32
// re-rank of near-ties -> in-register exact residual update (L2-hot emb
// gather). Final: out = x - r_final via LDS transpose -> full-line stores.
// ws: [0,2MB) hi frags f16 [4][64 ct][8 j][64 lane][8]
//     [2MB,+16KB) e2b = sum(e^2)+512 ; then f64 loss[4]

#define NUM_Q   4
#define KCODE   1024
#define DIM     256
#define NROWS   131072
#define QELEMS  33554432
#define MARGIN_FLAG 0.40f
#define KMASK   0xFFFFFC00u

typedef _Float16 f16x8 __attribute__((ext_vector_type(8)));
typedef float    f32x4 __attribute__((ext_vector_type(4)));

__device__ __forceinline__ float dqk(unsigned k) { return __uint_as_float(k & KMASK); }
__device__ __forceinline__ unsigned umin2(unsigned a, unsigned b) { return a < b ? a : b; }
__device__ __forceinline__ unsigned umax2(unsigned a, unsigned b) { return a > b ? a : b; }

// ---------------------------------------------------------------- prep
__global__ __launch_bounds__(64) void rvq_prep(const float* __restrict__ emb,
                                               _Float16* __restrict__ efrag,
                                               float* __restrict__ e2b,
                                               double* __restrict__ loss)
{
    const int bid  = blockIdx.x;            // layer*64 + ct
    const int lane = threadIdx.x;
    const int layer = bid >> 6;
    const int c = (bid & 63)*16 + (lane & 15);
    const int g = lane >> 4;
    const float* ep = emb + ((size_t)layer*KCODE + c)*DIM;

    double s2 = 0.0;
    #pragma unroll
    for (int j = 0; j < 8; ++j) {
        const int k0 = j*32 + 8*g;
        float4 a = *(const float4*)(ep + k0);
        float4 b = *(const float4*)(ep + k0 + 4);
        float v[8] = {a.x,a.y,a.z,a.w,b.x,b.y,b.z,b.w};
        f16x8 hh;
        #pragma unroll
        for (int x = 0; x < 8; ++x) {
            double dv = (double)v[x];
            s2 += dv*dv;
            hh[x] = (_Float16)(-2.0f*v[x]);          // fold -2 exactly
        }
        *(f16x8*)(efrag + ((size_t)(bid*8 + j)*64 + lane)*8) = hh;
    }
    s2 += __shfl_xor(s2, 16);
    s2 += __shfl_xor(s2, 32);
    if (g == 0) e2b[layer*KCODE + c] = (float)(s2 + 512.0);  // bias keeps keys positive
    if (bid == 0 && lane < 4) loss[lane] = 0.0;
}

// ------------- bit-exact numpy fp32 distance (validated r4-r9) -------------
__device__ __forceinline__ float np_sq128(const float* p) {
    #pragma clang fp contract(off)
    float s[16], U[4];
    #pragma unroll
    for (int l = 0; l < 16; ++l) {
        s[l] = ((p[l]*p[l] + p[16+l]*p[16+l]) + (p[32+l]*p[32+l] + p[48+l]*p[48+l]))
             + ((p[64+l]*p[64+l] + p[80+l]*p[80+l]) + (p[96+l]*p[96+l] + p[112+l]*p[112+l]));
    }
    #pragma unroll
    for (int i = 0; i < 4; ++i) U[i] = (s[i] + s[i+8]) + (s[i+4] + s[i+12]);
    return (U[0] + U[2]) + (U[1] + U[3]);
}
__device__ __forceinline__ float np_dist(const float* rp, const float* ep) {
    #pragma clang fp contract(off)
    float m = 0.f;
    #pragma unroll
    for (int kb = 0; kb < 16; ++kb) {          // batched loads, exact FMA order
        float a[16];
        #pragma unroll
        for (int x = 0; x < 4; ++x) {
            float4 v = *(const float4*)(ep + kb*16 + x*4);
            a[x*4+0]=v.x; a[x*4+1]=v.y; a[x*4+2]=v.z; a[x*4+3]=v.w;
        }
        #pragma unroll
        for (int x = 0; x < 16; ++x) m = __builtin_fmaf(rp[kb*16+x], a[x], m);
    }
    float se = np_sq128(ep) + np_sq128(ep + 128);
    float sr = np_sq128(rp) + np_sq128(rp + 128);
    return (sr + se) - 2.0f*m;
}

// ---------------------------------------------------------------- fused
__global__ __launch_bounds__(256, 2) void rvq_fused(
    const float* __restrict__ x, float* __restrict__ out,
    const float* __restrict__ emb,        // [4][1024][256]
    const _Float16* __restrict__ efrag,   // [4][64][8][64][8]
    const float* __restrict__ e2b,        // [4][1024] (biased +512)
    float* __restrict__ idx_base,         // [4][NROWS] as float
    double* __restrict__ loss)            // [4]
{
    __shared__ __align__(16) _Float16 lt[2][8][64][8];   // 16 KB dbuf
    __shared__ __align__(16) float    e2l[KCODE];        // 4 KB
    __shared__ __align__(16) float    s_remu[4][DIM];    // 4 KB
    __shared__ __align__(16) float    stg[4][4][260];    // 16.6 KB transpose staging
    __shared__ double wsum[4];

    const int tid  = threadIdx.x;
    const int w    = tid >> 6;
    const int lane = tid & 63;
    const int col  = lane & 15;
    const int g    = lane >> 4;
    const int r0   = blockIdx.x*128 + w*32;   // 32 rows per wave

    // load rows from x -> fp32 regs + hi-fp16 fragments
    f32x4 rv4[2][16];
    f16x8 rh[2][8];
    #pragma unroll
    for (int t = 0; t < 2; ++t) {
        const float* rp = x + (size_t)(r0 + 16*t + col)*DIM + 8*g;
        #pragma unroll
        for (int j = 0; j < 8; ++j) {
            rv4[t][2*j]   = *(const f32x4*)(rp + j*32);
            rv4[t][2*j+1] = *(const f32x4*)(rp + j*32 + 4);
            #pragma unroll
            for (int xx = 0; xx < 4; ++xx) {
                rh[t][j][xx]   = (_Float16)rv4[t][2*j][xx];
                rh[t][j][4+xx] = (_Float16)rv4[t][2*j+1][xx];
            }
        }
    }

    const uint4* gsrc = (const uint4*)efrag;     // 512 uint4 per 8KB tile

    #pragma unroll 1
    for (int q = 0; q < NUM_Q; ++q) {
        const float* embq = emb + (size_t)q*KCODE*DIM;

        // stage e2l slice + tile 0 for this layer
        *(f32x4*)(e2l + tid*4) = *(const f32x4*)(e2b + q*KCODE + tid*4);
        {
            const uint4* gt = gsrc + (size_t)q*64*512;
            uint4 s0 = gt[tid], s1 = gt[256 + tid];
            uint4* lw = (uint4*)&lt[0][0][0][0];
            lw[tid] = s0; lw[256 + tid] = s1;
        }
        __syncthreads();
        if (q > 0 && tid == 0)            // previous layer's loss (wsum stable)
            atomicAdd(loss + (q-1), wsum[0]+wsum[1]+wsum[2]+wsum[3]);

        unsigned k1[2] = {~0u, ~0u}, k2[2] = {~0u, ~0u};
        unsigned k3[2] = {~0u, ~0u}, k4[2] = {~0u, ~0u};
        const unsigned kor = (unsigned)(g << 2);

        for (int ct = 0; ct < 64; ++ct) {
            const int cur = ct & 1;
            uint4 p0, p1;
            if (ct < 63) {                       // prefetch next tile to regs
                const uint4* gt = gsrc + ((size_t)q*64 + ct + 1)*512;
                p0 = gt[tid]; p1 = gt[256 + tid];
            }
            f32x4 e2v = *(const f32x4*)(e2l + ct*16 + 4*g);
            f32x4 acc[2] = {e2v, e2v};           // C-init = e2 + 512
            #pragma unroll
            for (int j = 0; j < 8; ++j) {
                f16x8 ah = *(const f16x8*)&lt[cur][j][lane][0];
                acc[0] = __builtin_amdgcn_mfma_f32_16x16x32_f16(ah, rh[0][j], acc[0], 0,0,0);
                acc[1] = __builtin_amdgcn_mfma_f32_16x16x32_f16(ah, rh[1][j], acc[1], 0,0,0);
            }
            const unsigned ctb = (unsigned)(ct << 4);
            #pragma unroll
            for (int t = 0; t < 2; ++t) {
                #pragma unroll
                for (int r = 0; r < 4; ++r) {
                    unsigned key = (__float_as_uint(acc[t][r]) & KMASK) | kor | (ctb + (unsigned)r);
                    unsigned a1 = umin2(k1[t], key), b1 = umax2(k1[t], key); k1[t] = a1;
                    unsigned a2 = umin2(k2[t], b1),  b2 = umax2(k2[t], b1);  k2[t] = a2;
                    unsigned a3 = umin2(k3[t], b2),  b3 = umax2(k3[t], b2);  k3[t] = a3;
                    k4[t] = umin2(k4[t], b3);
                }
            }
            if (ct < 63) {
                uint4* lw = (uint4*)&lt[cur^1][0][0][0];
                lw[tid] = p0; lw[256 + tid] = p1;
            }
            __syncthreads();
        }

        // per-row min, flags, re-rank (staged from regs), index write
        int fidx[2];
        #pragma unroll
        for (int t = 0; t < 2; ++t) {
            unsigned gm = k1[t];
            gm = umin2(gm, __shfl_xor(gm, 16));
            gm = umin2(gm, __shfl_xor(gm, 32));
            float thr = dqk(gm) + MARGIN_FLAG;
            bool c1 = (k1[t] != gm) && (dqk(k1[t]) < thr);
            bool c2 = dqk(k2[t]) < thr;
            bool c3 = dqk(k3[t]) < thr;
            bool c4 = dqk(k4[t]) < thr;
            unsigned long long b = __ballot(c1 || c2 || c3 || c4);
            unsigned rowm = (unsigned)((b | (b>>16) | (b>>32) | (b>>48)) & 0xFFFFull);
            fidx[t] = (int)(gm & 1023u);

            unsigned m = rowm;
            while (m) {
                int p = __ffs(m) - 1; m &= m - 1;
                if (col == p) {                  // stage row p to LDS from regs
                    #pragma unroll
                    for (int j = 0; j < 8; ++j) {
                        *(f32x4*)&s_remu[w][j*32 + 8*g]     = rv4[t][2*j];
                        *(f32x4*)&s_remu[w][j*32 + 8*g + 4] = rv4[t][2*j+1];
                    }
                }
                asm volatile("s_waitcnt lgkmcnt(0)" ::: "memory");
                int srcl = ((lane & 12) << 2) | p;          // 16 eval lanes
                unsigned s1 = __shfl(k1[t], srcl), s2 = __shfl(k2[t], srcl);
                unsigned s3 = __shfl(k3[t], srcl), s4 = __shfl(k4[t], srcl);
                int slot = lane & 3;
                unsigned ksel = slot == 0 ? s1 : (slot == 1 ? s2 : (slot == 2 ? s3 : s4));
                float thr_p = __shfl(thr, p);
                bool valid = (lane < 16) && (dqk(ksel) < thr_p);
                float d = 3.4e38f;
                int   cc = 0x7FFFFFFF;
                if (valid) {
                    cc = (int)(ksel & 1023u);
                    d  = np_dist(&s_remu[w][0], embq + (size_t)cc*DIM);
                }
                #pragma unroll
                for (int off = 1; off < 64; off <<= 1) {
                    float od = __shfl_xor(d, off);
                    int   oc = __shfl_xor(cc, off);
                    if (od < d || (od == d && oc < cc)) { d = od; cc = oc; }
                }
                if (col == p) fidx[t] = cc;
            }
            if (lane < 16) idx_base[(size_t)q*NROWS + r0 + 16*t + lane] = (float)fidx[t];
        }

        // in-register residual update (exact fp32 3-op chain) + loss; rebuild rh
        double lacc = 0.0;
        #pragma unroll
        for (int t = 0; t < 2; ++t) {
            const float* ep = embq + (size_t)fidx[t]*DIM + 8*g;
            #pragma unroll
            for (int j = 0; j < 8; ++j) {
                #pragma clang fp contract(off)
                f32x4 e0 = *(const f32x4*)(ep + j*32);
                f32x4 e1 = *(const f32x4*)(ep + j*32 + 4);
                #pragma unroll
                for (int xx = 0; xx < 4; ++xx) {
                    float r1 = rv4[t][2*j][xx];
                    float tq1 = e0[xx] - r1;
                    float qs1 = r1 + tq1;
                    rv4[t][2*j][xx] = r1 - qs1;
                    lacc += (double)tq1 * (double)tq1;
                    float r2 = rv4[t][2*j+1][xx];
                    float tq2 = e1[xx] - r2;
                    float qs2 = r2 + tq2;
                    rv4[t][2*j+1][xx] = r2 - qs2;
                    lacc += (double)tq2 * (double)tq2;
                }
                #pragma unroll
                for (int xx = 0; xx < 4; ++xx) {
                    rh[t][j][xx]   = (_Float16)rv4[t][2*j][xx];
                    rh[t][j][4+xx] = (_Float16)rv4[t][2*j+1][xx];
                }
            }
        }
        #pragma unroll
        for (int o = 32; o; o >>= 1) lacc += __shfl_xor(lacc, o);
        if (lane == 0) wsum[w] = lacc;
        // note: wsum consumed at next layer's post-staging barrier (or below)
    }
    __syncthreads();
    if (tid == 0) atomicAdd(loss + (NUM_Q-1), wsum[0]+wsum[1]+wsum[2]+wsum[3]);

    // final: out = x - r_final. LDS transpose (frag layout -> row layout),
    // coalesced full-1KB-line x reads and out stores (no write-allocate).
    #pragma unroll
    for (int t = 0; t < 2; ++t) {
        for (int c = 0; c < 4; ++c) {
            if ((col >> 2) == c) {               // 16 active lanes: 4 rows x 4 g
                #pragma unroll
                for (int j = 0; j < 8; ++j) {
                    *(f32x4*)&stg[w][col & 3][j*32 + 8*g]     = rv4[t][2*j];
                    *(f32x4*)&stg[w][col & 3][j*32 + 8*g + 4] = rv4[t][2*j+1];
                }
            }
            asm volatile("s_waitcnt lgkmcnt(0)" ::: "memory");
            #pragma unroll
            for (int k = 0; k < 4; ++k) {
                int row = r0 + 16*t + 4*c + k;
                f32x4 rf = *(const f32x4*)&stg[w][k][4*lane];
                f32x4 xv = *(const f32x4*)(x + (size_t)row*DIM + 4*lane);
                f32x4 ov;
                #pragma unroll
                for (int xx = 0; xx < 4; ++xx) ov[xx] = xv[xx] - rf[xx];
                *(f32x4*)(out + (size_t)row*DIM + 4*lane) = ov;
            }
            asm volatile("s_waitcnt lgkmcnt(0)" ::: "memory");  // drain reads before re-stage
        }
    }
}

// ---------------------------------------------------------------- loss finalize
__global__ void rvq_loss(const double* __restrict__ loss, float* __restrict__ lossout)
{
    double tot = (loss[0]+loss[1]+loss[2]+loss[3]) * (1.0/(double)QELEMS);
    lossout[0] = (float)(1.25*tot);
    lossout[1] = (float)(0.25*tot);
    lossout[2] = (float)tot;
}

// ---------------------------------------------------------------- launch
extern "C" void kernel_launch(void* const* d_in, const int* in_sizes, int n_in,
                              void* d_out, int out_size, void* d_ws, size_t ws_size,
                              hipStream_t stream)
{
    (void)in_sizes; (void)n_in; (void)out_size; (void)ws_size;
    const float* x   = (const float*)d_in[0];
    const float* emb = (const float*)d_in[1];
    float* out      = (float*)d_out;
    float* idx_base = out + QELEMS;
    float* loss_out = out + QELEMS + (size_t)NUM_Q*NROWS;

    _Float16* efrag = (_Float16*)d_ws;                              // 2 MB
    float*    e2b   = (float*)((char*)d_ws + 2u*1024u*1024u);       // 16 KB
    double*   loss  = (double*)((char*)d_ws + 2u*1024u*1024u + 16384u);

    rvq_prep<<<NUM_Q*64, 64, 0, stream>>>(emb, efrag, e2b, loss);
    rvq_fused<<<NROWS/128, 256, 0, stream>>>(x, out, emb, efrag, e2b, idx_base, loss);
    rvq_loss<<<1, 1, 0, stream>>>(loss, loss_out);
}